// Round 1
// baseline (376.688 us; speedup 1.0000x reference)
//
#include <hip/hip_runtime.h>
#include <stdint.h>
#include <math.h>

#define BB  4096
#define CC  32000
#define KK  30
#define TPB 256

// Order-preserving float->uint mapping (no NaNs in this data).
__device__ __forceinline__ uint32_t fkey(float f) {
  uint32_t u = __float_as_uint(f);
  return (u & 0x80000000u) ? ~u : (u | 0x80000000u);
}

// Exact top-30 (value desc, ties -> lowest index) of one row of CC floats.
// 256 threads; results (indices) to outIdx[0..29] in LDS. waveBuf: 4*KK u64.
__device__ __forceinline__ void topk_row(const float* __restrict__ row,
                                         uint32_t* outIdx,
                                         unsigned long long* waveBuf) {
  const int tid  = threadIdx.x;
  const int lane = tid & 63;
  const int w    = tid >> 6;

  // per-thread sorted top-8 (u0 largest ... u7 smallest), key 0 = empty
  uint32_t u0=0,u1=0,u2=0,u3=0,u4=0,u5=0,u6=0,u7=0;
  uint32_t j0=0,j1=0,j2=0,j3=0,j4=0,j5=0,j6=0,j7=0;

#define SWP(a,b) { uint32_t tu=u##a; u##a=u##b; u##b=tu; \
                   uint32_t tj=j##a; j##a=j##b; j##b=tj; }
#define PROC(xv, ii) { uint32_t uk = fkey(xv);                       \
    if (uk > u7) {                                                   \
      u7 = uk; j7 = (uint32_t)(ii);                                  \
      if (u7>u6) SWP(7,6)                                            \
      if (u6>u5) SWP(6,5)                                            \
      if (u5>u4) SWP(5,4)                                            \
      if (u4>u3) SWP(4,3)                                            \
      if (u3>u2) SWP(3,2)                                            \
      if (u2>u1) SWP(2,1)                                            \
      if (u1>u0) SWP(1,0)                                            \
    } }

  // stream the row as float4, strided for coalescing
  const float4* row4 = reinterpret_cast<const float4*>(row);
  for (int j = tid; j < CC/4; j += TPB) {
    float4 v = row4[j];
    int b = j << 2;
    PROC(v.x, b);
    PROC(v.y, b + 1);
    PROC(v.z, b + 2);
    PROC(v.w, b + 3);
  }
#undef PROC
#undef SWP

  // pack (value-key, ~idx): bigger value wins; equal value -> smaller idx wins
  unsigned long long k0 = ((unsigned long long)u0 << 32) | (uint32_t)~j0;
  unsigned long long k1 = ((unsigned long long)u1 << 32) | (uint32_t)~j1;
  unsigned long long k2 = ((unsigned long long)u2 << 32) | (uint32_t)~j2;
  unsigned long long k3 = ((unsigned long long)u3 << 32) | (uint32_t)~j3;
  unsigned long long k4 = ((unsigned long long)u4 << 32) | (uint32_t)~j4;
  unsigned long long k5 = ((unsigned long long)u5 << 32) | (uint32_t)~j5;
  unsigned long long k6 = ((unsigned long long)u6 << 32) | (uint32_t)~j6;
  unsigned long long k7 = ((unsigned long long)u7 << 32) | (uint32_t)~j7;

  // per-wave top-30 by 30 rounds of 64-lane butterfly max (keys are unique)
  unsigned long long keep = 0ull;
  for (int round = 0; round < KK; ++round) {
    unsigned long long m = k0;   // local list sorted: k0 is this lane's max
#pragma unroll
    for (int d = 1; d < 64; d <<= 1) {
      unsigned long long o = __shfl_xor(m, d, 64);
      if (o > m) m = o;
    }
    if (k0 == m) { k0=k1; k1=k2; k2=k3; k3=k4; k4=k5; k5=k6; k6=k7; k7=0ull; }
    if (lane == round) keep = m;
  }

  __syncthreads();                       // waveBuf free from any previous use
  if (lane < KK) waveBuf[w * KK + lane] = keep;
  __syncthreads();

  // wave 0: merge 4*30 = 120 candidates -> exact top-30
  if (w == 0) {
    unsigned long long a  = (lane < 2 * KK) ? waveBuf[2 * lane]     : 0ull;
    unsigned long long b2 = (lane < 2 * KK) ? waveBuf[2 * lane + 1] : 0ull;
    unsigned long long keep2 = 0ull;
    for (int round = 0; round < KK; ++round) {
      unsigned long long m = (a > b2) ? a : b2;
#pragma unroll
      for (int d = 1; d < 64; d <<= 1) {
        unsigned long long o = __shfl_xor(m, d, 64);
        if (o > m) m = o;
      }
      if (a == m)       { a = b2; b2 = 0ull; }
      else if (b2 == m) { b2 = 0ull; }
      if (lane == round) keep2 = m;
    }
    if (lane < KK) outIdx[lane] = ~((uint32_t)(keep2 & 0xffffffffull));
  }
  __syncthreads();
}

__global__ __launch_bounds__(TPB)
void rowloss_kernel(const float* __restrict__ logits,
                    const float* __restrict__ targets,
                    float* __restrict__ ws) {
  const int r   = blockIdx.x;
  const int tid = threadIdx.x;

  __shared__ uint32_t trueIdx[KK];
  __shared__ uint32_t predIdx[KK];
  __shared__ unsigned long long waveBuf[4 * KK];

  const float* lrow = logits  + (size_t)r * CC;
  const float* trow = targets + (size_t)r * CC;

  topk_row(trow, trueIdx, waveBuf);   // top-30 of targets -> true indices
  topk_row(lrow, predIdx, waveBuf);   // top-30 of logits  -> pred indices

  // lanes 0..29 (wave 0): loss terms at true indices + overlap count
  float lossv = 0.f;
  int   ov    = 0;
  if (tid < KK) {
    uint32_t ti = trueIdx[tid];
    float x = lrow[ti];                       // gather (L1/L2 hot)
    float p = 1.f / (1.f + expf(-x));         // sigmoid, TEMPERATURE = 1
    lossv = -logf(p + 1e-7f);
#pragma unroll
    for (int jj = 0; jj < KK; ++jj) ov += (ti == predIdx[jj]) ? 1 : 0;
  }
  if (tid < 64) {
#pragma unroll
    for (int d = 32; d >= 1; d >>= 1) {
      lossv += __shfl_down(lossv, d, 64);
      ov    += __shfl_down(ov,    d, 64);
    }
    if (tid == 0) {
      float loss = lossv / (float)KK;
      float wgt  = 1.f - (float)ov / (float)KK;
      ws[r] = loss * wgt;
    }
  }
}

__global__ __launch_bounds__(TPB)
void reduce_kernel(const float* __restrict__ ws, float* __restrict__ out) {
  __shared__ float part[TPB / 64];
  const int tid = threadIdx.x;
  float s = 0.f;
  for (int i = tid; i < BB; i += TPB) s += ws[i];
#pragma unroll
  for (int d = 32; d >= 1; d >>= 1) s += __shfl_down(s, d, 64);
  if ((tid & 63) == 0) part[tid >> 6] = s;
  __syncthreads();
  if (tid == 0) {
    float t = 0.f;
#pragma unroll
    for (int i = 0; i < TPB / 64; ++i) t += part[i];
    out[0] = t / (float)BB;
  }
}

extern "C" void kernel_launch(void* const* d_in, const int* in_sizes, int n_in,
                              void* d_out, int out_size, void* d_ws, size_t ws_size,
                              hipStream_t stream) {
  const float* logits  = (const float*)d_in[0];
  const float* targets = (const float*)d_in[1];
  float* ws  = (float*)d_ws;       // BB floats of scratch (16 KB)
  float* out = (float*)d_out;

  hipLaunchKernelGGL(rowloss_kernel, dim3(BB), dim3(TPB), 0, stream,
                     logits, targets, ws);
  hipLaunchKernelGGL(reduce_kernel, dim3(1), dim3(TPB), 0, stream, ws, out);
}